// Round 5
// baseline (450.627 us; speedup 1.0000x reference)
//
#include <hip/hip_runtime.h>
#include <hip/hip_bf16.h>
#include <math.h>

// Problem: B=4, T=2048, C=1024, H=16, D=64, d_half=32
// Dataflow:
//   cast x, w_attn, w_proj -> bf16
//   qkvb = xb @ wab^T  with rope+rmsnorm fused into the q/k epilogue (bf16 out)
//   attn (bf16 MFMA flash, fixed-max softmax, fold-paired q-tiles,
//         LDS-instruction-minimized) -> yb
//   out  = yb @ wpb^T  (fp32 out)

#define TT 2048
#define CC 1024
#define HH 16
#define DD 64

typedef __attribute__((ext_vector_type(8))) short short8;
typedef __attribute__((ext_vector_type(4))) float f32x4;
typedef unsigned short ushort_t;

// fp32 -> bf16 (RNE, finite inputs only)
__device__ __forceinline__ ushort_t f2bf(float f) {
    unsigned u = __builtin_bit_cast(unsigned, f);
    u = (u + 0x7fffu + ((u >> 16) & 1u)) >> 16;
    return (ushort_t)u;
}

// ---------------------------------------------------------------------------
// float -> bf16 cast, 8 elements/thread
// ---------------------------------------------------------------------------
__global__ __launch_bounds__(256) void cast_bf16(const float* __restrict__ in,
                                                 ushort_t* __restrict__ out, int n8) {
    const int i = blockIdx.x * 256 + threadIdx.x;
    if (i >= n8) return;
    const float4* p = (const float4*)in + (size_t)i * 2;
    float4 f0 = p[0], f1 = p[1];
    short8 v;
    v[0] = (short)f2bf(f0.x); v[1] = (short)f2bf(f0.y);
    v[2] = (short)f2bf(f0.z); v[3] = (short)f2bf(f0.w);
    v[4] = (short)f2bf(f1.x); v[5] = (short)f2bf(f1.y);
    v[6] = (short)f2bf(f1.z); v[7] = (short)f2bf(f1.w);
    *(short8*)(out + (size_t)i * 8) = v;
}

// ---------------------------------------------------------------------------
// bf16 MFMA GEMM (m97 structure): C = A[M,K] * B[N,K]^T, 128x128 tile, BK=32.
// OUTF32 selects fp32 vs bf16 C.
// ---------------------------------------------------------------------------
template <bool OUTF32>
__global__ __launch_bounds__(256) void gemm_bt(const ushort_t* __restrict__ A,
                                               const ushort_t* __restrict__ B,
                                               void* __restrict__ C,
                                               int M, int N, int K) {
    __shared__ ushort_t As[128 * 32];
    __shared__ ushort_t Bs[128 * 32];

    const int tid  = threadIdx.x;
    const int wv   = tid >> 6;
    const int ln   = tid & 63;
    const int quad = ln >> 4;
    const int lm   = ln & 15;
    const int wm   = wv & 1;
    const int wn   = wv >> 1;
    const int rowC = blockIdx.y * 128;
    const int colC = blockIdx.x * 128;

    const int srow = wv * 16 + (ln >> 2);
    const int skq  = (ln & 3) * 8;

    f32x4 acc[4][4];
#pragma unroll
    for (int i = 0; i < 4; ++i)
#pragma unroll
        for (int j = 0; j < 4; ++j) acc[i][j] = (f32x4){0.f, 0.f, 0.f, 0.f};

    for (int k0 = 0; k0 < K; k0 += 32) {
        __syncthreads();
#pragma unroll
        for (int half = 0; half < 2; ++half) {
            const ushort_t* gA = A + (size_t)(rowC + half * 64 + srow) * K + k0 + skq;
            const ushort_t* gB = B + (size_t)(colC + half * 64 + srow) * K + k0 + skq;
            ushort_t* lA = As + (half * 64 + wv * 16) * 32;
            ushort_t* lB = Bs + (half * 64 + wv * 16) * 32;
            __builtin_amdgcn_global_load_lds(
                (const __attribute__((address_space(1))) unsigned int*)gA,
                (__attribute__((address_space(3))) unsigned int*)lA, 16, 0, 0);
            __builtin_amdgcn_global_load_lds(
                (const __attribute__((address_space(1))) unsigned int*)gB,
                (__attribute__((address_space(3))) unsigned int*)lB, 16, 0, 0);
        }
        __syncthreads();

        short8 af[4], bf[4];
#pragma unroll
        for (int mt = 0; mt < 4; ++mt)
            af[mt] = *(const short8*)&As[(wm * 64 + mt * 16 + lm) * 32 + quad * 8];
#pragma unroll
        for (int nt = 0; nt < 4; ++nt)
            bf[nt] = *(const short8*)&Bs[(wn * 64 + nt * 16 + lm) * 32 + quad * 8];
#pragma unroll
        for (int mt = 0; mt < 4; ++mt)
#pragma unroll
            for (int nt = 0; nt < 4; ++nt)
                acc[mt][nt] = __builtin_amdgcn_mfma_f32_16x16x32_bf16(
                    af[mt], bf[nt], acc[mt][nt], 0, 0, 0);
    }

#pragma unroll
    for (int mt = 0; mt < 4; ++mt)
#pragma unroll
        for (int r = 0; r < 4; ++r) {
            const size_t row = rowC + wm * 64 + mt * 16 + quad * 4 + r;
#pragma unroll
            for (int nt = 0; nt < 4; ++nt) {
                const size_t col = colC + wn * 64 + nt * 16 + lm;
                if (OUTF32) ((float*)C)[row * N + col] = acc[mt][nt][r];
                else        ((ushort_t*)C)[row * N + col] = f2bf(acc[mt][nt][r]);
            }
        }
}

// ---------------------------------------------------------------------------
// GEMM1 with fused rope+rmsnorm epilogue (see round 4 notes).
// ---------------------------------------------------------------------------
__global__ __launch_bounds__(256) void gemm_qkv(const ushort_t* __restrict__ A,
                                                const ushort_t* __restrict__ B,
                                                ushort_t* __restrict__ C,
                                                const float* __restrict__ cosb,
                                                const float* __restrict__ sinb,
                                                int M, int N, int K) {
    __shared__ ushort_t As[128 * 32];
    __shared__ ushort_t Bs[128 * 32];

    const int tid  = threadIdx.x;
    const int wv   = tid >> 6;
    const int ln   = tid & 63;
    const int quad = ln >> 4;
    const int lm   = ln & 15;
    const int wm   = wv & 1;
    const int wn   = wv >> 1;
    const int rowC = blockIdx.y * 128;
    const int colC = blockIdx.x * 128;

    const int srow = wv * 16 + (ln >> 2);
    const int skq  = (ln & 3) * 8;

    f32x4 acc[4][4];
#pragma unroll
    for (int i = 0; i < 4; ++i)
#pragma unroll
        for (int j = 0; j < 4; ++j) acc[i][j] = (f32x4){0.f, 0.f, 0.f, 0.f};

    for (int k0 = 0; k0 < K; k0 += 32) {
        __syncthreads();
#pragma unroll
        for (int half = 0; half < 2; ++half) {
            const ushort_t* gA = A + (size_t)(rowC + half * 64 + srow) * K + k0 + skq;
            const ushort_t* gB = B + (size_t)(colC + half * 64 + srow) * K + k0 + skq;
            ushort_t* lA = As + (half * 64 + wv * 16) * 32;
            ushort_t* lB = Bs + (half * 64 + wv * 16) * 32;
            __builtin_amdgcn_global_load_lds(
                (const __attribute__((address_space(1))) unsigned int*)gA,
                (__attribute__((address_space(3))) unsigned int*)lA, 16, 0, 0);
            __builtin_amdgcn_global_load_lds(
                (const __attribute__((address_space(1))) unsigned int*)gB,
                (__attribute__((address_space(3))) unsigned int*)lB, 16, 0, 0);
        }
        __syncthreads();

        short8 af[4], bf[4];
#pragma unroll
        for (int mt = 0; mt < 4; ++mt)
            af[mt] = *(const short8*)&As[(wm * 64 + mt * 16 + lm) * 32 + quad * 8];
#pragma unroll
        for (int nt = 0; nt < 4; ++nt)
            bf[nt] = *(const short8*)&Bs[(wn * 64 + nt * 16 + lm) * 32 + quad * 8];
#pragma unroll
        for (int mt = 0; mt < 4; ++mt)
#pragma unroll
            for (int nt = 0; nt < 4; ++nt)
                acc[mt][nt] = __builtin_amdgcn_mfma_f32_16x16x32_bf16(
                    af[mt], bf[nt], acc[mt][nt], 0, 0, 0);
    }

    const bool isqk = colC < 2 * CC;   // q or k section
#pragma unroll
    for (int mt = 0; mt < 4; ++mt)
#pragma unroll
        for (int r = 0; r < 4; ++r) {
            const int row = rowC + wm * 64 + mt * 16 + quad * 4 + r;
            ushort_t* Cp = C + (size_t)row * N + colC + wn * 64 + lm;
            if (isqk) {
                const int t = row & (TT - 1);
                float ss = 0.f;
#pragma unroll
                for (int nt = 0; nt < 4; ++nt) ss += acc[mt][nt][r] * acc[mt][nt][r];
                ss += __shfl_xor(ss, 1);
                ss += __shfl_xor(ss, 2);
                ss += __shfl_xor(ss, 4);
                ss += __shfl_xor(ss, 8);
                const float rinv = rsqrtf(ss * (1.0f / 64.0f) + 1e-6f);
                const float c0 = cosb[t * 32 + lm];
                const float c1 = cosb[t * 32 + 16 + lm];
                const float s0 = sinb[t * 32 + lm];
                const float s1 = sinb[t * 32 + 16 + lm];
                const float o0 = acc[mt][0][r] * c0 + acc[mt][2][r] * s0;
                const float o1 = acc[mt][1][r] * c1 + acc[mt][3][r] * s1;
                const float o2 = acc[mt][2][r] * c0 - acc[mt][0][r] * s0;
                const float o3 = acc[mt][3][r] * c1 - acc[mt][1][r] * s1;
                Cp[0]  = f2bf(o0 * rinv);
                Cp[16] = f2bf(o1 * rinv);
                Cp[32] = f2bf(o2 * rinv);
                Cp[48] = f2bf(o3 * rinv);
            } else {
#pragma unroll
                for (int nt = 0; nt < 4; ++nt) Cp[nt * 16] = f2bf(acc[mt][nt][r]);
            }
        }
}

// ---------------------------------------------------------------------------
// bf16 MFMA flash attention, fixed-max softmax, fold-paired q-tiles.
// Round-5 changes (LDS-instruction minimization):
//  - V staged via register 4x4 micro-transpose: 4 ds_write_b64 (was 16 b16)
//  - kf/vf fragments read once per tile, shared by both q-halves (2 Ps bufs)
//  - exp via __builtin_amdgcn_exp2f with folded scale/shift
// ---------------------------------------------------------------------------
__global__ __launch_bounds__(256, 4) void attn_mfma(const ushort_t* __restrict__ qkv,
                                                    ushort_t* __restrict__ y) {
    const int qp = blockIdx.x;   // 0..15
    const int h  = blockIdx.y;   // 0..15
    const int b  = blockIdx.z;   // 0..3
    const int tid  = threadIdx.x;
    const int w    = tid >> 6;
    const int lane = tid & 63;
    const int quad = lane >> 4;
    const int lm   = lane & 15;
    const int qtA = qp, qtB = 31 - qp;

    __shared__ ushort_t Ks[64][72];     // K[n][d]
    __shared__ ushort_t Vt[64][72];     // V^T[d][n]
    __shared__ ushort_t PsA[4][16][72]; // per-wave P[m][n], q-half A
    __shared__ ushort_t PsB[4][16][72]; // per-wave P[m][n], q-half B

    short8 qfA[2], qfB[2];
    {
        const ushort_t* qa = qkv + (size_t)(b * TT + qtA * 64 + w * 16 + lm) * (3 * CC) + h * DD;
        const ushort_t* qb = qkv + (size_t)(b * TT + qtB * 64 + w * 16 + lm) * (3 * CC) + h * DD;
        qfA[0] = *(const short8*)(qa + quad * 8);
        qfA[1] = *(const short8*)(qa + 32 + quad * 8);
        qfB[0] = *(const short8*)(qb + quad * 8);
        qfB[1] = *(const short8*)(qb + 32 + quad * 8);
    }

    f32x4 OA[4], OB[4];
#pragma unroll
    for (int dt = 0; dt < 4; ++dt) {
        OA[dt] = (f32x4){0.f, 0.f, 0.f, 0.f};
        OB[dt] = (f32x4){0.f, 0.f, 0.f, 0.f};
    }
    float psA[4] = {0.f, 0.f, 0.f, 0.f};
    float psB[4] = {0.f, 0.f, 0.f, 0.f};

    // K staging: row sn, 16-col segment sd
    const int sn = tid >> 2;
    const int sd = (tid & 3) * 16;
    // V staging (micro-transpose): d-block db, token-block tb
    const int db = tid & 15;
    const int tb = tid >> 4;

    // exp2 constants: p = 2^(s*0.125*log2e - 8*log2e)
    const float K_MUL = 0.125f * 1.44269504f;
    const float K_SUB = -8.f * 1.44269504f;

    for (int kt = 0; kt <= qtB; ++kt) {
        __syncthreads();
        {
            // K: 2 x b128 LDS writes
            const ushort_t* kp = qkv + (size_t)(b * TT + kt * 64 + sn) * (3 * CC) + CC + h * DD + sd;
            *(short8*)&Ks[sn][sd]     = *(const short8*)kp;
            *(short8*)&Ks[sn][sd + 8] = *(const short8*)(kp + 8);
            // V: 4 x ushort4 loads (rows tb*4..+3, cols db*4..+3) -> 4x4
            // register transpose -> 4 x ds_write_b64
            const ushort_t* vp = qkv + (size_t)(b * TT + kt * 64 + tb * 4) * (3 * CC) + 2 * CC + h * DD + db * 4;
            ushort4 r0 = *(const ushort4*)vp;
            ushort4 r1 = *(const ushort4*)(vp + 3 * CC);
            ushort4 r2 = *(const ushort4*)(vp + 6 * CC);
            ushort4 r3 = *(const ushort4*)(vp + 9 * CC);
            ushort4 w0 = {r0.x, r1.x, r2.x, r3.x};
            ushort4 w1 = {r0.y, r1.y, r2.y, r3.y};
            ushort4 w2 = {r0.z, r1.z, r2.z, r3.z};
            ushort4 w3 = {r0.w, r1.w, r2.w, r3.w};
            *(ushort4*)&Vt[db * 4 + 0][tb * 4] = w0;
            *(ushort4*)&Vt[db * 4 + 1][tb * 4] = w1;
            *(ushort4*)&Vt[db * 4 + 2][tb * 4] = w2;
            *(ushort4*)&Vt[db * 4 + 3][tb * 4] = w3;
        }
        __syncthreads();

        const bool doA = (kt <= qtA);
        const bool dgA = (kt == qtA);
        const bool dgB = (kt == qtB);

        // ---- K fragments once per tile ----
        short8 kf[2][4];
#pragma unroll
        for (int kk = 0; kk < 2; ++kk)
#pragma unroll
            for (int nt = 0; nt < 4; ++nt)
                kf[kk][nt] = *(const short8*)&Ks[nt * 16 + lm][kk * 32 + quad * 8];

        // ---- S + softmax for half A ----
        if (doA) {
            f32x4 sf[4];
#pragma unroll
            for (int nt = 0; nt < 4; ++nt) sf[nt] = (f32x4){0.f, 0.f, 0.f, 0.f};
#pragma unroll
            for (int kk = 0; kk < 2; ++kk)
#pragma unroll
                for (int nt = 0; nt < 4; ++nt)
                    sf[nt] = __builtin_amdgcn_mfma_f32_16x16x32_bf16(qfA[kk], kf[kk][nt], sf[nt], 0, 0, 0);
#pragma unroll
            for (int r = 0; r < 4; ++r) {
                const int rloc = w * 16 + quad * 4 + r;
#pragma unroll
                for (int nt = 0; nt < 4; ++nt) {
                    float e = fmaf(sf[nt][r], K_MUL, K_SUB);
                    if (dgA) e = (nt * 16 + lm <= rloc) ? e : -1e30f;
                    const float p = __builtin_amdgcn_exp2f(e);
                    psA[r] += p;
                    PsA[w][quad * 4 + r][nt * 16 + lm] = f2bf(p);
                }
            }
        }

        // ---- S + softmax for half B (always) ----
        {
            f32x4 sf[4];
#pragma unroll
            for (int nt = 0; nt < 4; ++nt) sf[nt] = (f32x4){0.f, 0.f, 0.f, 0.f};
#pragma unroll
            for (int kk = 0; kk < 2; ++kk)
#pragma unroll
                for (int nt = 0; nt < 4; ++nt)
                    sf[nt] = __builtin_amdgcn_mfma_f32_16x16x32_bf16(qfB[kk], kf[kk][nt], sf[nt], 0, 0, 0);
#pragma unroll
            for (int r = 0; r < 4; ++r) {
                const int rloc = w * 16 + quad * 4 + r;
#pragma unroll
                for (int nt = 0; nt < 4; ++nt) {
                    float e = fmaf(sf[nt][r], K_MUL, K_SUB);
                    if (dgB) e = (nt * 16 + lm <= rloc) ? e : -1e30f;
                    const float p = __builtin_amdgcn_exp2f(e);
                    psB[r] += p;
                    PsB[w][quad * 4 + r][nt * 16 + lm] = f2bf(p);
                }
            }
        }

        // ---- V fragments once per tile (kf registers dead now) ----
        short8 vf[2][4];
#pragma unroll
        for (int kk = 0; kk < 2; ++kk)
#pragma unroll
            for (int dt = 0; dt < 4; ++dt)
                vf[kk][dt] = *(const short8*)&Vt[dt * 16 + lm][kk * 32 + quad * 8];

        // ---- PV for half A ----
        if (doA) {
#pragma unroll
            for (int kk = 0; kk < 2; ++kk) {
                short8 pf = *(const short8*)&PsA[w][lm][kk * 32 + quad * 8];
#pragma unroll
                for (int dt = 0; dt < 4; ++dt)
                    OA[dt] = __builtin_amdgcn_mfma_f32_16x16x32_bf16(pf, vf[kk][dt], OA[dt], 0, 0, 0);
            }
        }
        // ---- PV for half B ----
#pragma unroll
        for (int kk = 0; kk < 2; ++kk) {
            short8 pf = *(const short8*)&PsB[w][lm][kk * 32 + quad * 8];
#pragma unroll
            for (int dt = 0; dt < 4; ++dt)
                OB[dt] = __builtin_amdgcn_mfma_f32_16x16x32_bf16(pf, vf[kk][dt], OB[dt], 0, 0, 0);
        }
    }

    // epilogue: reduce row sums once, scale, store
    auto epi = [&](f32x4 (&O)[4], float (&ps)[4], int qt) {
#pragma unroll
        for (int r = 0; r < 4; ++r) {
            float l = ps[r];
            l += __shfl_xor(l, 1);
            l += __shfl_xor(l, 2);
            l += __shfl_xor(l, 4);
            l += __shfl_xor(l, 8);
            const float inv_l = 1.f / l;
            ushort_t* yp = y + (size_t)(b * TT + qt * 64 + w * 16 + quad * 4 + r) * CC + h * DD + lm;
#pragma unroll
            for (int dt = 0; dt < 4; ++dt) yp[dt * 16] = f2bf(O[dt][r] * inv_l);
        }
    };
    epi(OA, psA, qtA);
    epi(OB, psB, qtB);
}

// ---------------------------------------------------------------------------
extern "C" void kernel_launch(void* const* d_in, const int* in_sizes, int n_in,
                              void* d_out, int out_size, void* d_ws, size_t ws_size,
                              hipStream_t stream) {
    const float* x      = (const float*)d_in[0];   // (4,2048,1024)
    const float* cosb   = (const float*)d_in[1];   // (1,2048,1,32)
    const float* sinb   = (const float*)d_in[2];
    const float* w_attn = (const float*)d_in[3];   // (3072,1024)
    const float* w_proj = (const float*)d_in[4];   // (1024,1024)
    float* out = (float*)d_out;                    // (4,2048,1024)

    // workspace layout (bf16 elements)
    ushort_t* qkvb = (ushort_t*)d_ws;                       // 8192*3072
    ushort_t* yb   = qkvb + (size_t)8192 * 3072;            // 8192*1024
    ushort_t* xb   = yb   + (size_t)8192 * 1024;            // 8192*1024
    ushort_t* wab  = xb   + (size_t)8192 * 1024;            // 3072*1024
    ushort_t* wpb  = wab  + (size_t)3072 * 1024;            // 1024*1024

    cast_bf16<<<(8192 * 1024 / 8 + 255) / 256, 256, 0, stream>>>(x, xb, 8192 * 1024 / 8);
    cast_bf16<<<(3072 * 1024 / 8 + 255) / 256, 256, 0, stream>>>(w_attn, wab, 3072 * 1024 / 8);
    cast_bf16<<<(1024 * 1024 / 8 + 255) / 256, 256, 0, stream>>>(w_proj, wpb, 1024 * 1024 / 8);

    // qkv = x @ w_attn^T with fused rope+rmsnorm on q,k
    gemm_qkv<<<dim3(3072 / 128, 8192 / 128), 256, 0, stream>>>(
        xb, wab, qkvb, cosb, sinb, 8192, 3072, 1024);

    // causal attention -> yb
    attn_mfma<<<dim3(16, HH, 4), 256, 0, stream>>>(qkvb, yb);

    // out = y @ w_proj^T (fp32 out)
    gemm_bt<true><<<dim3(1024 / 128, 8192 / 128), 256, 0, stream>>>(
        yb, wpb, out, 8192, 1024, 1024);
}

// Round 6
// 397.539 us; speedup vs baseline: 1.1335x; 1.1335x over previous
//
#include <hip/hip_runtime.h>
#include <hip/hip_bf16.h>
#include <math.h>

// Problem: B=4, T=2048, C=1024, H=16, D=64, d_half=32
// Dataflow:
//   cast x, w_attn, w_proj -> bf16
//   qkvb = xb @ wab^T  with rope+rmsnorm fused into the q/k epilogue (bf16 out)
//   attn (bf16 MFMA flash, fixed-max softmax, fold-paired q-tiles) -> yb
//   out  = yb @ wpb^T  (fp32 out)
// Round-6 attn: round-4 structure (kf in-loop), V micro-transpose staging,
// exp2 softmax, vf hoisted once per tile with double Ps buffers.
// Register budget lesson (round 5): at __launch_bounds__(256,4) keep peak
// live VGPRs <= ~110 or the compiler spills to scratch (WRITE_SIZE 20x).

#define TT 2048
#define CC 1024
#define HH 16
#define DD 64

typedef __attribute__((ext_vector_type(8))) short short8;
typedef __attribute__((ext_vector_type(4))) float f32x4;
typedef unsigned short ushort_t;

// fp32 -> bf16 (RNE, finite inputs only)
__device__ __forceinline__ ushort_t f2bf(float f) {
    unsigned u = __builtin_bit_cast(unsigned, f);
    u = (u + 0x7fffu + ((u >> 16) & 1u)) >> 16;
    return (ushort_t)u;
}

// ---------------------------------------------------------------------------
// float -> bf16 cast, 8 elements/thread
// ---------------------------------------------------------------------------
__global__ __launch_bounds__(256) void cast_bf16(const float* __restrict__ in,
                                                 ushort_t* __restrict__ out, int n8) {
    const int i = blockIdx.x * 256 + threadIdx.x;
    if (i >= n8) return;
    const float4* p = (const float4*)in + (size_t)i * 2;
    float4 f0 = p[0], f1 = p[1];
    short8 v;
    v[0] = (short)f2bf(f0.x); v[1] = (short)f2bf(f0.y);
    v[2] = (short)f2bf(f0.z); v[3] = (short)f2bf(f0.w);
    v[4] = (short)f2bf(f1.x); v[5] = (short)f2bf(f1.y);
    v[6] = (short)f2bf(f1.z); v[7] = (short)f2bf(f1.w);
    *(short8*)(out + (size_t)i * 8) = v;
}

// ---------------------------------------------------------------------------
// bf16 MFMA GEMM (m97 structure): C = A[M,K] * B[N,K]^T, 128x128 tile, BK=32.
// OUTF32 selects fp32 vs bf16 C.
// ---------------------------------------------------------------------------
template <bool OUTF32>
__global__ __launch_bounds__(256) void gemm_bt(const ushort_t* __restrict__ A,
                                               const ushort_t* __restrict__ B,
                                               void* __restrict__ C,
                                               int M, int N, int K) {
    __shared__ ushort_t As[128 * 32];
    __shared__ ushort_t Bs[128 * 32];

    const int tid  = threadIdx.x;
    const int wv   = tid >> 6;
    const int ln   = tid & 63;
    const int quad = ln >> 4;
    const int lm   = ln & 15;
    const int wm   = wv & 1;
    const int wn   = wv >> 1;
    const int rowC = blockIdx.y * 128;
    const int colC = blockIdx.x * 128;

    const int srow = wv * 16 + (ln >> 2);
    const int skq  = (ln & 3) * 8;

    f32x4 acc[4][4];
#pragma unroll
    for (int i = 0; i < 4; ++i)
#pragma unroll
        for (int j = 0; j < 4; ++j) acc[i][j] = (f32x4){0.f, 0.f, 0.f, 0.f};

    for (int k0 = 0; k0 < K; k0 += 32) {
        __syncthreads();
#pragma unroll
        for (int half = 0; half < 2; ++half) {
            const ushort_t* gA = A + (size_t)(rowC + half * 64 + srow) * K + k0 + skq;
            const ushort_t* gB = B + (size_t)(colC + half * 64 + srow) * K + k0 + skq;
            ushort_t* lA = As + (half * 64 + wv * 16) * 32;
            ushort_t* lB = Bs + (half * 64 + wv * 16) * 32;
            __builtin_amdgcn_global_load_lds(
                (const __attribute__((address_space(1))) unsigned int*)gA,
                (__attribute__((address_space(3))) unsigned int*)lA, 16, 0, 0);
            __builtin_amdgcn_global_load_lds(
                (const __attribute__((address_space(1))) unsigned int*)gB,
                (__attribute__((address_space(3))) unsigned int*)lB, 16, 0, 0);
        }
        __syncthreads();

        short8 af[4], bf[4];
#pragma unroll
        for (int mt = 0; mt < 4; ++mt)
            af[mt] = *(const short8*)&As[(wm * 64 + mt * 16 + lm) * 32 + quad * 8];
#pragma unroll
        for (int nt = 0; nt < 4; ++nt)
            bf[nt] = *(const short8*)&Bs[(wn * 64 + nt * 16 + lm) * 32 + quad * 8];
#pragma unroll
        for (int mt = 0; mt < 4; ++mt)
#pragma unroll
            for (int nt = 0; nt < 4; ++nt)
                acc[mt][nt] = __builtin_amdgcn_mfma_f32_16x16x32_bf16(
                    af[mt], bf[nt], acc[mt][nt], 0, 0, 0);
    }

#pragma unroll
    for (int mt = 0; mt < 4; ++mt)
#pragma unroll
        for (int r = 0; r < 4; ++r) {
            const size_t row = rowC + wm * 64 + mt * 16 + quad * 4 + r;
#pragma unroll
            for (int nt = 0; nt < 4; ++nt) {
                const size_t col = colC + wn * 64 + nt * 16 + lm;
                if (OUTF32) ((float*)C)[row * N + col] = acc[mt][nt][r];
                else        ((ushort_t*)C)[row * N + col] = f2bf(acc[mt][nt][r]);
            }
        }
}

// ---------------------------------------------------------------------------
// GEMM1 with fused rope+rmsnorm epilogue (see round 4 notes).
// ---------------------------------------------------------------------------
__global__ __launch_bounds__(256) void gemm_qkv(const ushort_t* __restrict__ A,
                                                const ushort_t* __restrict__ B,
                                                ushort_t* __restrict__ C,
                                                const float* __restrict__ cosb,
                                                const float* __restrict__ sinb,
                                                int M, int N, int K) {
    __shared__ ushort_t As[128 * 32];
    __shared__ ushort_t Bs[128 * 32];

    const int tid  = threadIdx.x;
    const int wv   = tid >> 6;
    const int ln   = tid & 63;
    const int quad = ln >> 4;
    const int lm   = ln & 15;
    const int wm   = wv & 1;
    const int wn   = wv >> 1;
    const int rowC = blockIdx.y * 128;
    const int colC = blockIdx.x * 128;

    const int srow = wv * 16 + (ln >> 2);
    const int skq  = (ln & 3) * 8;

    f32x4 acc[4][4];
#pragma unroll
    for (int i = 0; i < 4; ++i)
#pragma unroll
        for (int j = 0; j < 4; ++j) acc[i][j] = (f32x4){0.f, 0.f, 0.f, 0.f};

    for (int k0 = 0; k0 < K; k0 += 32) {
        __syncthreads();
#pragma unroll
        for (int half = 0; half < 2; ++half) {
            const ushort_t* gA = A + (size_t)(rowC + half * 64 + srow) * K + k0 + skq;
            const ushort_t* gB = B + (size_t)(colC + half * 64 + srow) * K + k0 + skq;
            ushort_t* lA = As + (half * 64 + wv * 16) * 32;
            ushort_t* lB = Bs + (half * 64 + wv * 16) * 32;
            __builtin_amdgcn_global_load_lds(
                (const __attribute__((address_space(1))) unsigned int*)gA,
                (__attribute__((address_space(3))) unsigned int*)lA, 16, 0, 0);
            __builtin_amdgcn_global_load_lds(
                (const __attribute__((address_space(1))) unsigned int*)gB,
                (__attribute__((address_space(3))) unsigned int*)lB, 16, 0, 0);
        }
        __syncthreads();

        short8 af[4], bf[4];
#pragma unroll
        for (int mt = 0; mt < 4; ++mt)
            af[mt] = *(const short8*)&As[(wm * 64 + mt * 16 + lm) * 32 + quad * 8];
#pragma unroll
        for (int nt = 0; nt < 4; ++nt)
            bf[nt] = *(const short8*)&Bs[(wn * 64 + nt * 16 + lm) * 32 + quad * 8];
#pragma unroll
        for (int mt = 0; mt < 4; ++mt)
#pragma unroll
            for (int nt = 0; nt < 4; ++nt)
                acc[mt][nt] = __builtin_amdgcn_mfma_f32_16x16x32_bf16(
                    af[mt], bf[nt], acc[mt][nt], 0, 0, 0);
    }

    const bool isqk = colC < 2 * CC;   // q or k section
#pragma unroll
    for (int mt = 0; mt < 4; ++mt)
#pragma unroll
        for (int r = 0; r < 4; ++r) {
            const int row = rowC + wm * 64 + mt * 16 + quad * 4 + r;
            ushort_t* Cp = C + (size_t)row * N + colC + wn * 64 + lm;
            if (isqk) {
                const int t = row & (TT - 1);
                float ss = 0.f;
#pragma unroll
                for (int nt = 0; nt < 4; ++nt) ss += acc[mt][nt][r] * acc[mt][nt][r];
                ss += __shfl_xor(ss, 1);
                ss += __shfl_xor(ss, 2);
                ss += __shfl_xor(ss, 4);
                ss += __shfl_xor(ss, 8);
                const float rinv = rsqrtf(ss * (1.0f / 64.0f) + 1e-6f);
                const float c0 = cosb[t * 32 + lm];
                const float c1 = cosb[t * 32 + 16 + lm];
                const float s0 = sinb[t * 32 + lm];
                const float s1 = sinb[t * 32 + 16 + lm];
                const float o0 = acc[mt][0][r] * c0 + acc[mt][2][r] * s0;
                const float o1 = acc[mt][1][r] * c1 + acc[mt][3][r] * s1;
                const float o2 = acc[mt][2][r] * c0 - acc[mt][0][r] * s0;
                const float o3 = acc[mt][3][r] * c1 - acc[mt][1][r] * s1;
                Cp[0]  = f2bf(o0 * rinv);
                Cp[16] = f2bf(o1 * rinv);
                Cp[32] = f2bf(o2 * rinv);
                Cp[48] = f2bf(o3 * rinv);
            } else {
#pragma unroll
                for (int nt = 0; nt < 4; ++nt) Cp[nt * 16] = f2bf(acc[mt][nt][r]);
            }
        }
}

// ---------------------------------------------------------------------------
// bf16 MFMA flash attention, fixed-max softmax, fold-paired q-tiles.
// Round-6: round-4 structure with (a) V staged via register 4x4
// micro-transpose (4 ds_write_b64), (b) exp2 softmax, (c) vf fragments read
// once per tile (double Ps buffers so PV_A and PV_B run back-to-back).
// kf fragments stay in-loop (transient) to keep VGPR pressure < 128.
// ---------------------------------------------------------------------------
__global__ __launch_bounds__(256, 4) void attn_mfma(const ushort_t* __restrict__ qkv,
                                                    ushort_t* __restrict__ y) {
    const int qp = blockIdx.x;   // 0..15
    const int h  = blockIdx.y;   // 0..15
    const int b  = blockIdx.z;   // 0..3
    const int tid  = threadIdx.x;
    const int w    = tid >> 6;
    const int lane = tid & 63;
    const int quad = lane >> 4;
    const int lm   = lane & 15;
    const int qtA = qp, qtB = 31 - qp;

    __shared__ ushort_t Ks[64][72];     // K[n][d]
    __shared__ ushort_t Vt[64][72];     // V^T[d][n]
    __shared__ ushort_t PsA[4][16][72]; // per-wave P[m][n], q-half A
    __shared__ ushort_t PsB[4][16][72]; // per-wave P[m][n], q-half B

    short8 qfA[2], qfB[2];
    {
        const ushort_t* qa = qkv + (size_t)(b * TT + qtA * 64 + w * 16 + lm) * (3 * CC) + h * DD;
        const ushort_t* qb = qkv + (size_t)(b * TT + qtB * 64 + w * 16 + lm) * (3 * CC) + h * DD;
        qfA[0] = *(const short8*)(qa + quad * 8);
        qfA[1] = *(const short8*)(qa + 32 + quad * 8);
        qfB[0] = *(const short8*)(qb + quad * 8);
        qfB[1] = *(const short8*)(qb + 32 + quad * 8);
    }

    f32x4 OA[4], OB[4];
#pragma unroll
    for (int dt = 0; dt < 4; ++dt) {
        OA[dt] = (f32x4){0.f, 0.f, 0.f, 0.f};
        OB[dt] = (f32x4){0.f, 0.f, 0.f, 0.f};
    }
    float psA[4] = {0.f, 0.f, 0.f, 0.f};
    float psB[4] = {0.f, 0.f, 0.f, 0.f};

    // K staging: row sn, 16-col segment sd
    const int sn = tid >> 2;
    const int sd = (tid & 3) * 16;
    // V staging (micro-transpose): d-block db, token-block tb
    const int db = tid & 15;
    const int tb = tid >> 4;

    // exp2 constants: p = 2^(s*0.125*log2e - 8*log2e)
    const float K_MUL = 0.125f * 1.44269504f;
    const float K_SUB = -8.f * 1.44269504f;

    for (int kt = 0; kt <= qtB; ++kt) {
        __syncthreads();
        {
            // K: 2 x b128 LDS writes
            const ushort_t* kp = qkv + (size_t)(b * TT + kt * 64 + sn) * (3 * CC) + CC + h * DD + sd;
            *(short8*)&Ks[sn][sd]     = *(const short8*)kp;
            *(short8*)&Ks[sn][sd + 8] = *(const short8*)(kp + 8);
            // V: 4 x ushort4 global loads -> 4x4 register transpose ->
            // 4 x ds_write_b64
            const ushort_t* vp = qkv + (size_t)(b * TT + kt * 64 + tb * 4) * (3 * CC) + 2 * CC + h * DD + db * 4;
            ushort4 r0 = *(const ushort4*)vp;
            ushort4 r1 = *(const ushort4*)(vp + 3 * CC);
            ushort4 r2 = *(const ushort4*)(vp + 6 * CC);
            ushort4 r3 = *(const ushort4*)(vp + 9 * CC);
            ushort4 w0 = {r0.x, r1.x, r2.x, r3.x};
            ushort4 w1 = {r0.y, r1.y, r2.y, r3.y};
            ushort4 w2 = {r0.z, r1.z, r2.z, r3.z};
            ushort4 w3 = {r0.w, r1.w, r2.w, r3.w};
            *(ushort4*)&Vt[db * 4 + 0][tb * 4] = w0;
            *(ushort4*)&Vt[db * 4 + 1][tb * 4] = w1;
            *(ushort4*)&Vt[db * 4 + 2][tb * 4] = w2;
            *(ushort4*)&Vt[db * 4 + 3][tb * 4] = w3;
        }
        __syncthreads();

        const bool doA = (kt <= qtA);
        const bool dgA = (kt == qtA);
        const bool dgB = (kt == qtB);

        // ---- S + softmax, half A (kf read in-loop, transient regs) ----
        if (doA) {
            f32x4 sf[4];
#pragma unroll
            for (int nt = 0; nt < 4; ++nt) sf[nt] = (f32x4){0.f, 0.f, 0.f, 0.f};
#pragma unroll
            for (int kk = 0; kk < 2; ++kk)
#pragma unroll
                for (int nt = 0; nt < 4; ++nt) {
                    short8 kfv = *(const short8*)&Ks[nt * 16 + lm][kk * 32 + quad * 8];
                    sf[nt] = __builtin_amdgcn_mfma_f32_16x16x32_bf16(qfA[kk], kfv, sf[nt], 0, 0, 0);
                }
#pragma unroll
            for (int r = 0; r < 4; ++r) {
                const int rloc = w * 16 + quad * 4 + r;
#pragma unroll
                for (int nt = 0; nt < 4; ++nt) {
                    float e = fmaf(sf[nt][r], K_MUL, K_SUB);
                    if (dgA) e = (nt * 16 + lm <= rloc) ? e : -1e30f;
                    const float p = __builtin_amdgcn_exp2f(e);
                    psA[r] += p;
                    PsA[w][quad * 4 + r][nt * 16 + lm] = f2bf(p);
                }
            }
        }

        // ---- S + softmax, half B (always) ----
        {
            f32x4 sf[4];
#pragma unroll
            for (int nt = 0; nt < 4; ++nt) sf[nt] = (f32x4){0.f, 0.f, 0.f, 0.f};
#pragma unroll
            for (int kk = 0; kk < 2; ++kk)
#pragma unroll
                for (int nt = 0; nt < 4; ++nt) {
                    short8 kfv = *(const short8*)&Ks[nt * 16 + lm][kk * 32 + quad * 8];
                    sf[nt] = __builtin_amdgcn_mfma_f32_16x16x32_bf16(qfB[kk], kfv, sf[nt], 0, 0, 0);
                }
#pragma unroll
            for (int r = 0; r < 4; ++r) {
                const int rloc = w * 16 + quad * 4 + r;
#pragma unroll
                for (int nt = 0; nt < 4; ++nt) {
                    float e = fmaf(sf[nt][r], K_MUL, K_SUB);
                    if (dgB) e = (nt * 16 + lm <= rloc) ? e : -1e30f;
                    const float p = __builtin_amdgcn_exp2f(e);
                    psB[r] += p;
                    PsB[w][quad * 4 + r][nt * 16 + lm] = f2bf(p);
                }
            }
        }

        // ---- V fragments once per tile; PV_A then PV_B ----
        short8 vf[2][4];
#pragma unroll
        for (int kk = 0; kk < 2; ++kk)
#pragma unroll
            for (int dt = 0; dt < 4; ++dt)
                vf[kk][dt] = *(const short8*)&Vt[dt * 16 + lm][kk * 32 + quad * 8];

        if (doA) {
#pragma unroll
            for (int kk = 0; kk < 2; ++kk) {
                short8 pf = *(const short8*)&PsA[w][lm][kk * 32 + quad * 8];
#pragma unroll
                for (int dt = 0; dt < 4; ++dt)
                    OA[dt] = __builtin_amdgcn_mfma_f32_16x16x32_bf16(pf, vf[kk][dt], OA[dt], 0, 0, 0);
            }
        }
#pragma unroll
        for (int kk = 0; kk < 2; ++kk) {
            short8 pf = *(const short8*)&PsB[w][lm][kk * 32 + quad * 8];
#pragma unroll
            for (int dt = 0; dt < 4; ++dt)
                OB[dt] = __builtin_amdgcn_mfma_f32_16x16x32_bf16(pf, vf[kk][dt], OB[dt], 0, 0, 0);
        }
    }

    // epilogue: reduce row sums once, scale, store
    auto epi = [&](f32x4 (&O)[4], float (&ps)[4], int qt) {
#pragma unroll
        for (int r = 0; r < 4; ++r) {
            float l = ps[r];
            l += __shfl_xor(l, 1);
            l += __shfl_xor(l, 2);
            l += __shfl_xor(l, 4);
            l += __shfl_xor(l, 8);
            const float inv_l = 1.f / l;
            ushort_t* yp = y + (size_t)(b * TT + qt * 64 + w * 16 + quad * 4 + r) * CC + h * DD + lm;
#pragma unroll
            for (int dt = 0; dt < 4; ++dt) yp[dt * 16] = f2bf(O[dt][r] * inv_l);
        }
    };
    epi(OA, psA, qtA);
    epi(OB, psB, qtB);
}

// ---------------------------------------------------------------------------
extern "C" void kernel_launch(void* const* d_in, const int* in_sizes, int n_in,
                              void* d_out, int out_size, void* d_ws, size_t ws_size,
                              hipStream_t stream) {
    const float* x      = (const float*)d_in[0];   // (4,2048,1024)
    const float* cosb   = (const float*)d_in[1];   // (1,2048,1,32)
    const float* sinb   = (const float*)d_in[2];
    const float* w_attn = (const float*)d_in[3];   // (3072,1024)
    const float* w_proj = (const float*)d_in[4];   // (1024,1024)
    float* out = (float*)d_out;                    // (4,2048,1024)

    // workspace layout (bf16 elements)
    ushort_t* qkvb = (ushort_t*)d_ws;                       // 8192*3072
    ushort_t* yb   = qkvb + (size_t)8192 * 3072;            // 8192*1024
    ushort_t* xb   = yb   + (size_t)8192 * 1024;            // 8192*1024
    ushort_t* wab  = xb   + (size_t)8192 * 1024;            // 3072*1024
    ushort_t* wpb  = wab  + (size_t)3072 * 1024;            // 1024*1024

    cast_bf16<<<(8192 * 1024 / 8 + 255) / 256, 256, 0, stream>>>(x, xb, 8192 * 1024 / 8);
    cast_bf16<<<(3072 * 1024 / 8 + 255) / 256, 256, 0, stream>>>(w_attn, wab, 3072 * 1024 / 8);
    cast_bf16<<<(1024 * 1024 / 8 + 255) / 256, 256, 0, stream>>>(w_proj, wpb, 1024 * 1024 / 8);

    // qkv = x @ w_attn^T with fused rope+rmsnorm on q,k
    gemm_qkv<<<dim3(3072 / 128, 8192 / 128), 256, 0, stream>>>(
        xb, wab, qkvb, cosb, sinb, 8192, 3072, 1024);

    // causal attention -> yb
    attn_mfma<<<dim3(16, HH, 4), 256, 0, stream>>>(qkvb, yb);

    // out = y @ w_proj^T (fp32 out)
    gemm_bt<true><<<dim3(1024 / 128, 8192 / 128), 256, 0, stream>>>(
        yb, wpb, out, 8192, 1024, 1024);
}

// Round 7
// 315.190 us; speedup vs baseline: 1.4297x; 1.2613x over previous
//
#include <hip/hip_runtime.h>
#include <hip/hip_bf16.h>
#include <math.h>

// Problem: B=4, T=2048, C=1024, H=16, D=64, d_half=32
// Dataflow:
//   cast x, w_attn, w_proj -> bf16
//   qkvb = xb @ wab^T  with rope+rmsnorm fused into the q/k epilogue (bf16 out)
//   attn (bf16 MFMA flash, fixed-max softmax, fold-paired q-tiles) -> yb
//   out  = yb @ wpb^T  (fp32 out)
//
// Round-7 attn: EXACT round-4 phase structure (kf AND vf read in-loop,
// single Ps buffer) + V micro-transpose staging + exp2 softmax.
// HARD RULE (learned rounds 5-6 via WRITE_SIZE 270-330 MB spill signature):
// at __launch_bounds__(256,4) no fragment array may be held live across
// phase boundaries; only transient in-phase fragments. Round 4 = 60 VGPR,
// 16 MB WRITE_SIZE; any cross-phase hoist spilled.

#define TT 2048
#define CC 1024
#define HH 16
#define DD 64

typedef __attribute__((ext_vector_type(8))) short short8;
typedef __attribute__((ext_vector_type(4))) float f32x4;
typedef unsigned short ushort_t;

// fp32 -> bf16 (RNE, finite inputs only)
__device__ __forceinline__ ushort_t f2bf(float f) {
    unsigned u = __builtin_bit_cast(unsigned, f);
    u = (u + 0x7fffu + ((u >> 16) & 1u)) >> 16;
    return (ushort_t)u;
}

// ---------------------------------------------------------------------------
// float -> bf16 cast, 8 elements/thread
// ---------------------------------------------------------------------------
__global__ __launch_bounds__(256) void cast_bf16(const float* __restrict__ in,
                                                 ushort_t* __restrict__ out, int n8) {
    const int i = blockIdx.x * 256 + threadIdx.x;
    if (i >= n8) return;
    const float4* p = (const float4*)in + (size_t)i * 2;
    float4 f0 = p[0], f1 = p[1];
    short8 v;
    v[0] = (short)f2bf(f0.x); v[1] = (short)f2bf(f0.y);
    v[2] = (short)f2bf(f0.z); v[3] = (short)f2bf(f0.w);
    v[4] = (short)f2bf(f1.x); v[5] = (short)f2bf(f1.y);
    v[6] = (short)f2bf(f1.z); v[7] = (short)f2bf(f1.w);
    *(short8*)(out + (size_t)i * 8) = v;
}

// ---------------------------------------------------------------------------
// bf16 MFMA GEMM (m97 structure): C = A[M,K] * B[N,K]^T, 128x128 tile, BK=32.
// OUTF32 selects fp32 vs bf16 C.
// ---------------------------------------------------------------------------
template <bool OUTF32>
__global__ __launch_bounds__(256) void gemm_bt(const ushort_t* __restrict__ A,
                                               const ushort_t* __restrict__ B,
                                               void* __restrict__ C,
                                               int M, int N, int K) {
    __shared__ ushort_t As[128 * 32];
    __shared__ ushort_t Bs[128 * 32];

    const int tid  = threadIdx.x;
    const int wv   = tid >> 6;
    const int ln   = tid & 63;
    const int quad = ln >> 4;
    const int lm   = ln & 15;
    const int wm   = wv & 1;
    const int wn   = wv >> 1;
    const int rowC = blockIdx.y * 128;
    const int colC = blockIdx.x * 128;

    const int srow = wv * 16 + (ln >> 2);
    const int skq  = (ln & 3) * 8;

    f32x4 acc[4][4];
#pragma unroll
    for (int i = 0; i < 4; ++i)
#pragma unroll
        for (int j = 0; j < 4; ++j) acc[i][j] = (f32x4){0.f, 0.f, 0.f, 0.f};

    for (int k0 = 0; k0 < K; k0 += 32) {
        __syncthreads();
#pragma unroll
        for (int half = 0; half < 2; ++half) {
            const ushort_t* gA = A + (size_t)(rowC + half * 64 + srow) * K + k0 + skq;
            const ushort_t* gB = B + (size_t)(colC + half * 64 + srow) * K + k0 + skq;
            ushort_t* lA = As + (half * 64 + wv * 16) * 32;
            ushort_t* lB = Bs + (half * 64 + wv * 16) * 32;
            __builtin_amdgcn_global_load_lds(
                (const __attribute__((address_space(1))) unsigned int*)gA,
                (__attribute__((address_space(3))) unsigned int*)lA, 16, 0, 0);
            __builtin_amdgcn_global_load_lds(
                (const __attribute__((address_space(1))) unsigned int*)gB,
                (__attribute__((address_space(3))) unsigned int*)lB, 16, 0, 0);
        }
        __syncthreads();

        short8 af[4], bf[4];
#pragma unroll
        for (int mt = 0; mt < 4; ++mt)
            af[mt] = *(const short8*)&As[(wm * 64 + mt * 16 + lm) * 32 + quad * 8];
#pragma unroll
        for (int nt = 0; nt < 4; ++nt)
            bf[nt] = *(const short8*)&Bs[(wn * 64 + nt * 16 + lm) * 32 + quad * 8];
#pragma unroll
        for (int mt = 0; mt < 4; ++mt)
#pragma unroll
            for (int nt = 0; nt < 4; ++nt)
                acc[mt][nt] = __builtin_amdgcn_mfma_f32_16x16x32_bf16(
                    af[mt], bf[nt], acc[mt][nt], 0, 0, 0);
    }

#pragma unroll
    for (int mt = 0; mt < 4; ++mt)
#pragma unroll
        for (int r = 0; r < 4; ++r) {
            const size_t row = rowC + wm * 64 + mt * 16 + quad * 4 + r;
#pragma unroll
            for (int nt = 0; nt < 4; ++nt) {
                const size_t col = colC + wn * 64 + nt * 16 + lm;
                if (OUTF32) ((float*)C)[row * N + col] = acc[mt][nt][r];
                else        ((ushort_t*)C)[row * N + col] = f2bf(acc[mt][nt][r]);
            }
        }
}

// ---------------------------------------------------------------------------
// GEMM1 with fused rope+rmsnorm epilogue (see round 4 notes).
// ---------------------------------------------------------------------------
__global__ __launch_bounds__(256) void gemm_qkv(const ushort_t* __restrict__ A,
                                                const ushort_t* __restrict__ B,
                                                ushort_t* __restrict__ C,
                                                const float* __restrict__ cosb,
                                                const float* __restrict__ sinb,
                                                int M, int N, int K) {
    __shared__ ushort_t As[128 * 32];
    __shared__ ushort_t Bs[128 * 32];

    const int tid  = threadIdx.x;
    const int wv   = tid >> 6;
    const int ln   = tid & 63;
    const int quad = ln >> 4;
    const int lm   = ln & 15;
    const int wm   = wv & 1;
    const int wn   = wv >> 1;
    const int rowC = blockIdx.y * 128;
    const int colC = blockIdx.x * 128;

    const int srow = wv * 16 + (ln >> 2);
    const int skq  = (ln & 3) * 8;

    f32x4 acc[4][4];
#pragma unroll
    for (int i = 0; i < 4; ++i)
#pragma unroll
        for (int j = 0; j < 4; ++j) acc[i][j] = (f32x4){0.f, 0.f, 0.f, 0.f};

    for (int k0 = 0; k0 < K; k0 += 32) {
        __syncthreads();
#pragma unroll
        for (int half = 0; half < 2; ++half) {
            const ushort_t* gA = A + (size_t)(rowC + half * 64 + srow) * K + k0 + skq;
            const ushort_t* gB = B + (size_t)(colC + half * 64 + srow) * K + k0 + skq;
            ushort_t* lA = As + (half * 64 + wv * 16) * 32;
            ushort_t* lB = Bs + (half * 64 + wv * 16) * 32;
            __builtin_amdgcn_global_load_lds(
                (const __attribute__((address_space(1))) unsigned int*)gA,
                (__attribute__((address_space(3))) unsigned int*)lA, 16, 0, 0);
            __builtin_amdgcn_global_load_lds(
                (const __attribute__((address_space(1))) unsigned int*)gB,
                (__attribute__((address_space(3))) unsigned int*)lB, 16, 0, 0);
        }
        __syncthreads();

        short8 af[4], bf[4];
#pragma unroll
        for (int mt = 0; mt < 4; ++mt)
            af[mt] = *(const short8*)&As[(wm * 64 + mt * 16 + lm) * 32 + quad * 8];
#pragma unroll
        for (int nt = 0; nt < 4; ++nt)
            bf[nt] = *(const short8*)&Bs[(wn * 64 + nt * 16 + lm) * 32 + quad * 8];
#pragma unroll
        for (int mt = 0; mt < 4; ++mt)
#pragma unroll
            for (int nt = 0; nt < 4; ++nt)
                acc[mt][nt] = __builtin_amdgcn_mfma_f32_16x16x32_bf16(
                    af[mt], bf[nt], acc[mt][nt], 0, 0, 0);
    }

    const bool isqk = colC < 2 * CC;   // q or k section
#pragma unroll
    for (int mt = 0; mt < 4; ++mt)
#pragma unroll
        for (int r = 0; r < 4; ++r) {
            const int row = rowC + wm * 64 + mt * 16 + quad * 4 + r;
            ushort_t* Cp = C + (size_t)row * N + colC + wn * 64 + lm;
            if (isqk) {
                const int t = row & (TT - 1);
                float ss = 0.f;
#pragma unroll
                for (int nt = 0; nt < 4; ++nt) ss += acc[mt][nt][r] * acc[mt][nt][r];
                ss += __shfl_xor(ss, 1);
                ss += __shfl_xor(ss, 2);
                ss += __shfl_xor(ss, 4);
                ss += __shfl_xor(ss, 8);
                const float rinv = rsqrtf(ss * (1.0f / 64.0f) + 1e-6f);
                const float c0 = cosb[t * 32 + lm];
                const float c1 = cosb[t * 32 + 16 + lm];
                const float s0 = sinb[t * 32 + lm];
                const float s1 = sinb[t * 32 + 16 + lm];
                const float o0 = acc[mt][0][r] * c0 + acc[mt][2][r] * s0;
                const float o1 = acc[mt][1][r] * c1 + acc[mt][3][r] * s1;
                const float o2 = acc[mt][2][r] * c0 - acc[mt][0][r] * s0;
                const float o3 = acc[mt][3][r] * c1 - acc[mt][1][r] * s1;
                Cp[0]  = f2bf(o0 * rinv);
                Cp[16] = f2bf(o1 * rinv);
                Cp[32] = f2bf(o2 * rinv);
                Cp[48] = f2bf(o3 * rinv);
            } else {
#pragma unroll
                for (int nt = 0; nt < 4; ++nt) Cp[nt * 16] = f2bf(acc[mt][nt][r]);
            }
        }
}

// ---------------------------------------------------------------------------
// bf16 MFMA flash attention, fixed-max softmax, fold-paired q-tiles.
// Round-4 phase structure: each q-half's process() is fully self-contained
// (kf and vf read transiently inside). Single per-wave Ps buffer.
// Round-7 adds: V staged via register 4x4 micro-transpose (4 ds_write_b64),
// exp2 softmax with folded constants.
// ---------------------------------------------------------------------------
__global__ __launch_bounds__(256, 4) void attn_mfma(const ushort_t* __restrict__ qkv,
                                                    ushort_t* __restrict__ y) {
    const int qp = blockIdx.x;   // 0..15
    const int h  = blockIdx.y;   // 0..15
    const int b  = blockIdx.z;   // 0..3
    const int tid  = threadIdx.x;
    const int w    = tid >> 6;
    const int lane = tid & 63;
    const int quad = lane >> 4;
    const int lm   = lane & 15;
    const int qtA = qp, qtB = 31 - qp;

    __shared__ ushort_t Ks[64][72];    // K[n][d]
    __shared__ ushort_t Vt[64][72];    // V^T[d][n]
    __shared__ ushort_t Ps[4][16][72]; // per-wave P[m][n]

    short8 qfA[2], qfB[2];
    {
        const ushort_t* qa = qkv + (size_t)(b * TT + qtA * 64 + w * 16 + lm) * (3 * CC) + h * DD;
        const ushort_t* qb = qkv + (size_t)(b * TT + qtB * 64 + w * 16 + lm) * (3 * CC) + h * DD;
        qfA[0] = *(const short8*)(qa + quad * 8);
        qfA[1] = *(const short8*)(qa + 32 + quad * 8);
        qfB[0] = *(const short8*)(qb + quad * 8);
        qfB[1] = *(const short8*)(qb + 32 + quad * 8);
    }

    f32x4 OA[4], OB[4];
#pragma unroll
    for (int dt = 0; dt < 4; ++dt) {
        OA[dt] = (f32x4){0.f, 0.f, 0.f, 0.f};
        OB[dt] = (f32x4){0.f, 0.f, 0.f, 0.f};
    }
    float psA[4] = {0.f, 0.f, 0.f, 0.f};
    float psB[4] = {0.f, 0.f, 0.f, 0.f};

    // K staging: row sn, 16-col segment sd
    const int sn = tid >> 2;
    const int sd = (tid & 3) * 16;
    // V staging (micro-transpose): d-block db, token-block tb
    const int db = tid & 15;
    const int tb = tid >> 4;

    // exp2 constants: p = 2^(s*0.125*log2e - 8*log2e)
    const float K_MUL = 0.125f * 1.44269504f;
    const float K_SUB = -8.f * 1.44269504f;

    // self-contained per-tile, per-q-half processing (round-4 structure)
    auto process = [&](short8 (&qf)[2], f32x4 (&O)[4], float (&ps)[4], bool diag) {
        f32x4 sf[4];
#pragma unroll
        for (int nt = 0; nt < 4; ++nt) sf[nt] = (f32x4){0.f, 0.f, 0.f, 0.f};
#pragma unroll
        for (int kk = 0; kk < 2; ++kk)
#pragma unroll
            for (int nt = 0; nt < 4; ++nt) {
                short8 kf = *(const short8*)&Ks[nt * 16 + lm][kk * 32 + quad * 8];
                sf[nt] = __builtin_amdgcn_mfma_f32_16x16x32_bf16(qf[kk], kf, sf[nt], 0, 0, 0);
            }
#pragma unroll
        for (int r = 0; r < 4; ++r) {
            const int rloc = w * 16 + quad * 4 + r;
#pragma unroll
            for (int nt = 0; nt < 4; ++nt) {
                float e = fmaf(sf[nt][r], K_MUL, K_SUB);
                if (diag) e = (nt * 16 + lm <= rloc) ? e : -1e30f;
                const float p = __builtin_amdgcn_exp2f(e);
                ps[r] += p;
                Ps[w][quad * 4 + r][nt * 16 + lm] = f2bf(p);
            }
        }
#pragma unroll
        for (int kk = 0; kk < 2; ++kk) {
            short8 pf = *(const short8*)&Ps[w][lm][kk * 32 + quad * 8];
#pragma unroll
            for (int dt = 0; dt < 4; ++dt) {
                short8 vf = *(const short8*)&Vt[dt * 16 + lm][kk * 32 + quad * 8];
                O[dt] = __builtin_amdgcn_mfma_f32_16x16x32_bf16(pf, vf, O[dt], 0, 0, 0);
            }
        }
    };

    for (int kt = 0; kt <= qtB; ++kt) {
        __syncthreads();
        {
            // K: 2 x b128 LDS writes
            const ushort_t* kp = qkv + (size_t)(b * TT + kt * 64 + sn) * (3 * CC) + CC + h * DD + sd;
            *(short8*)&Ks[sn][sd]     = *(const short8*)kp;
            *(short8*)&Ks[sn][sd + 8] = *(const short8*)(kp + 8);
            // V: 4 x ushort4 global loads -> 4x4 register transpose ->
            // 4 x ds_write_b64 (transient regs only)
            const ushort_t* vp = qkv + (size_t)(b * TT + kt * 64 + tb * 4) * (3 * CC) + 2 * CC + h * DD + db * 4;
            ushort4 r0 = *(const ushort4*)vp;
            ushort4 r1 = *(const ushort4*)(vp + 3 * CC);
            ushort4 r2 = *(const ushort4*)(vp + 6 * CC);
            ushort4 r3 = *(const ushort4*)(vp + 9 * CC);
            ushort4 w0 = {r0.x, r1.x, r2.x, r3.x};
            ushort4 w1 = {r0.y, r1.y, r2.y, r3.y};
            ushort4 w2 = {r0.z, r1.z, r2.z, r3.z};
            ushort4 w3 = {r0.w, r1.w, r2.w, r3.w};
            *(ushort4*)&Vt[db * 4 + 0][tb * 4] = w0;
            *(ushort4*)&Vt[db * 4 + 1][tb * 4] = w1;
            *(ushort4*)&Vt[db * 4 + 2][tb * 4] = w2;
            *(ushort4*)&Vt[db * 4 + 3][tb * 4] = w3;
        }
        __syncthreads();

        if (kt <= qtA) process(qfA, OA, psA, kt == qtA);
        process(qfB, OB, psB, kt == qtB);
    }

    // epilogue: reduce row sums once, scale, store
    auto epi = [&](f32x4 (&O)[4], float (&ps)[4], int qt) {
#pragma unroll
        for (int r = 0; r < 4; ++r) {
            float l = ps[r];
            l += __shfl_xor(l, 1);
            l += __shfl_xor(l, 2);
            l += __shfl_xor(l, 4);
            l += __shfl_xor(l, 8);
            const float inv_l = 1.f / l;
            ushort_t* yp = y + (size_t)(b * TT + qt * 64 + w * 16 + quad * 4 + r) * CC + h * DD + lm;
#pragma unroll
            for (int dt = 0; dt < 4; ++dt) yp[dt * 16] = f2bf(O[dt][r] * inv_l);
        }
    };
    epi(OA, psA, qtA);
    epi(OB, psB, qtB);
}

// ---------------------------------------------------------------------------
extern "C" void kernel_launch(void* const* d_in, const int* in_sizes, int n_in,
                              void* d_out, int out_size, void* d_ws, size_t ws_size,
                              hipStream_t stream) {
    const float* x      = (const float*)d_in[0];   // (4,2048,1024)
    const float* cosb   = (const float*)d_in[1];   // (1,2048,1,32)
    const float* sinb   = (const float*)d_in[2];
    const float* w_attn = (const float*)d_in[3];   // (3072,1024)
    const float* w_proj = (const float*)d_in[4];   // (1024,1024)
    float* out = (float*)d_out;                    // (4,2048,1024)

    // workspace layout (bf16 elements)
    ushort_t* qkvb = (ushort_t*)d_ws;                       // 8192*3072
    ushort_t* yb   = qkvb + (size_t)8192 * 3072;            // 8192*1024
    ushort_t* xb   = yb   + (size_t)8192 * 1024;            // 8192*1024
    ushort_t* wab  = xb   + (size_t)8192 * 1024;            // 3072*1024
    ushort_t* wpb  = wab  + (size_t)3072 * 1024;            // 1024*1024

    cast_bf16<<<(8192 * 1024 / 8 + 255) / 256, 256, 0, stream>>>(x, xb, 8192 * 1024 / 8);
    cast_bf16<<<(3072 * 1024 / 8 + 255) / 256, 256, 0, stream>>>(w_attn, wab, 3072 * 1024 / 8);
    cast_bf16<<<(1024 * 1024 / 8 + 255) / 256, 256, 0, stream>>>(w_proj, wpb, 1024 * 1024 / 8);

    // qkv = x @ w_attn^T with fused rope+rmsnorm on q,k
    gemm_qkv<<<dim3(3072 / 128, 8192 / 128), 256, 0, stream>>>(
        xb, wab, qkvb, cosb, sinb, 8192, 3072, 1024);

    // causal attention -> yb
    attn_mfma<<<dim3(16, HH, 4), 256, 0, stream>>>(qkvb, yb);

    // out = y @ w_proj^T (fp32 out)
    gemm_bt<true><<<dim3(1024 / 128, 8192 / 128), 256, 0, stream>>>(
        yb, wpb, out, 8192, 1024, 1024);
}

// Round 8
// 313.506 us; speedup vs baseline: 1.4374x; 1.0054x over previous
//
#include <hip/hip_runtime.h>
#include <hip/hip_bf16.h>
#include <math.h>

// Problem: B=4, T=2048, C=1024, H=16, D=64, d_half=32
// Dataflow:
//   cast x, w_attn, w_proj -> bf16
//   qkvb = xb @ wab^T  with rope+rmsnorm fused into the q/k epilogue (bf16 out)
//   attn (bf16 MFMA flash, fixed-max softmax, fold-paired q-tiles,
//         S^T formulation) -> yb
//   out  = yb @ wpb^T  (fp32 out)
//
// Round-8 attn: compute S^T via mfma(kf, qf) so softmax is lane-local
// (row = lm), P written as packed ushort4 row-writes, O^T epilogue with
// vectorized stores, vf shared across the two folded q-halves.
// HARD RULE (rounds 5-6): no fragment array held live across phase
// boundaries at __launch_bounds__(256,4); sfA/sfB never coexist.

#define TT 2048
#define CC 1024
#define HH 16
#define DD 64

typedef __attribute__((ext_vector_type(8))) short short8;
typedef __attribute__((ext_vector_type(4))) float f32x4;
typedef unsigned short ushort_t;

// fp32 -> bf16 (RNE, finite inputs only)
__device__ __forceinline__ ushort_t f2bf(float f) {
    unsigned u = __builtin_bit_cast(unsigned, f);
    u = (u + 0x7fffu + ((u >> 16) & 1u)) >> 16;
    return (ushort_t)u;
}

// ---------------------------------------------------------------------------
// float -> bf16 cast, 8 elements/thread
// ---------------------------------------------------------------------------
__global__ __launch_bounds__(256) void cast_bf16(const float* __restrict__ in,
                                                 ushort_t* __restrict__ out, int n8) {
    const int i = blockIdx.x * 256 + threadIdx.x;
    if (i >= n8) return;
    const float4* p = (const float4*)in + (size_t)i * 2;
    float4 f0 = p[0], f1 = p[1];
    short8 v;
    v[0] = (short)f2bf(f0.x); v[1] = (short)f2bf(f0.y);
    v[2] = (short)f2bf(f0.z); v[3] = (short)f2bf(f0.w);
    v[4] = (short)f2bf(f1.x); v[5] = (short)f2bf(f1.y);
    v[6] = (short)f2bf(f1.z); v[7] = (short)f2bf(f1.w);
    *(short8*)(out + (size_t)i * 8) = v;
}

// ---------------------------------------------------------------------------
// bf16 MFMA GEMM (m97 structure): C = A[M,K] * B[N,K]^T, 128x128 tile, BK=32.
// OUTF32 selects fp32 vs bf16 C.
// ---------------------------------------------------------------------------
template <bool OUTF32>
__global__ __launch_bounds__(256) void gemm_bt(const ushort_t* __restrict__ A,
                                               const ushort_t* __restrict__ B,
                                               void* __restrict__ C,
                                               int M, int N, int K) {
    __shared__ ushort_t As[128 * 32];
    __shared__ ushort_t Bs[128 * 32];

    const int tid  = threadIdx.x;
    const int wv   = tid >> 6;
    const int ln   = tid & 63;
    const int quad = ln >> 4;
    const int lm   = ln & 15;
    const int wm   = wv & 1;
    const int wn   = wv >> 1;
    const int rowC = blockIdx.y * 128;
    const int colC = blockIdx.x * 128;

    const int srow = wv * 16 + (ln >> 2);
    const int skq  = (ln & 3) * 8;

    f32x4 acc[4][4];
#pragma unroll
    for (int i = 0; i < 4; ++i)
#pragma unroll
        for (int j = 0; j < 4; ++j) acc[i][j] = (f32x4){0.f, 0.f, 0.f, 0.f};

    for (int k0 = 0; k0 < K; k0 += 32) {
        __syncthreads();
#pragma unroll
        for (int half = 0; half < 2; ++half) {
            const ushort_t* gA = A + (size_t)(rowC + half * 64 + srow) * K + k0 + skq;
            const ushort_t* gB = B + (size_t)(colC + half * 64 + srow) * K + k0 + skq;
            ushort_t* lA = As + (half * 64 + wv * 16) * 32;
            ushort_t* lB = Bs + (half * 64 + wv * 16) * 32;
            __builtin_amdgcn_global_load_lds(
                (const __attribute__((address_space(1))) unsigned int*)gA,
                (__attribute__((address_space(3))) unsigned int*)lA, 16, 0, 0);
            __builtin_amdgcn_global_load_lds(
                (const __attribute__((address_space(1))) unsigned int*)gB,
                (__attribute__((address_space(3))) unsigned int*)lB, 16, 0, 0);
        }
        __syncthreads();

        short8 af[4], bf[4];
#pragma unroll
        for (int mt = 0; mt < 4; ++mt)
            af[mt] = *(const short8*)&As[(wm * 64 + mt * 16 + lm) * 32 + quad * 8];
#pragma unroll
        for (int nt = 0; nt < 4; ++nt)
            bf[nt] = *(const short8*)&Bs[(wn * 64 + nt * 16 + lm) * 32 + quad * 8];
#pragma unroll
        for (int mt = 0; mt < 4; ++mt)
#pragma unroll
            for (int nt = 0; nt < 4; ++nt)
                acc[mt][nt] = __builtin_amdgcn_mfma_f32_16x16x32_bf16(
                    af[mt], bf[nt], acc[mt][nt], 0, 0, 0);
    }

#pragma unroll
    for (int mt = 0; mt < 4; ++mt)
#pragma unroll
        for (int r = 0; r < 4; ++r) {
            const size_t row = rowC + wm * 64 + mt * 16 + quad * 4 + r;
#pragma unroll
            for (int nt = 0; nt < 4; ++nt) {
                const size_t col = colC + wn * 64 + nt * 16 + lm;
                if (OUTF32) ((float*)C)[row * N + col] = acc[mt][nt][r];
                else        ((ushort_t*)C)[row * N + col] = f2bf(acc[mt][nt][r]);
            }
        }
}

// ---------------------------------------------------------------------------
// GEMM1 with fused rope+rmsnorm epilogue (see round 4 notes).
// ---------------------------------------------------------------------------
__global__ __launch_bounds__(256) void gemm_qkv(const ushort_t* __restrict__ A,
                                                const ushort_t* __restrict__ B,
                                                ushort_t* __restrict__ C,
                                                const float* __restrict__ cosb,
                                                const float* __restrict__ sinb,
                                                int M, int N, int K) {
    __shared__ ushort_t As[128 * 32];
    __shared__ ushort_t Bs[128 * 32];

    const int tid  = threadIdx.x;
    const int wv   = tid >> 6;
    const int ln   = tid & 63;
    const int quad = ln >> 4;
    const int lm   = ln & 15;
    const int wm   = wv & 1;
    const int wn   = wv >> 1;
    const int rowC = blockIdx.y * 128;
    const int colC = blockIdx.x * 128;

    const int srow = wv * 16 + (ln >> 2);
    const int skq  = (ln & 3) * 8;

    f32x4 acc[4][4];
#pragma unroll
    for (int i = 0; i < 4; ++i)
#pragma unroll
        for (int j = 0; j < 4; ++j) acc[i][j] = (f32x4){0.f, 0.f, 0.f, 0.f};

    for (int k0 = 0; k0 < K; k0 += 32) {
        __syncthreads();
#pragma unroll
        for (int half = 0; half < 2; ++half) {
            const ushort_t* gA = A + (size_t)(rowC + half * 64 + srow) * K + k0 + skq;
            const ushort_t* gB = B + (size_t)(colC + half * 64 + srow) * K + k0 + skq;
            ushort_t* lA = As + (half * 64 + wv * 16) * 32;
            ushort_t* lB = Bs + (half * 64 + wv * 16) * 32;
            __builtin_amdgcn_global_load_lds(
                (const __attribute__((address_space(1))) unsigned int*)gA,
                (__attribute__((address_space(3))) unsigned int*)lA, 16, 0, 0);
            __builtin_amdgcn_global_load_lds(
                (const __attribute__((address_space(1))) unsigned int*)gB,
                (__attribute__((address_space(3))) unsigned int*)lB, 16, 0, 0);
        }
        __syncthreads();

        short8 af[4], bf[4];
#pragma unroll
        for (int mt = 0; mt < 4; ++mt)
            af[mt] = *(const short8*)&As[(wm * 64 + mt * 16 + lm) * 32 + quad * 8];
#pragma unroll
        for (int nt = 0; nt < 4; ++nt)
            bf[nt] = *(const short8*)&Bs[(wn * 64 + nt * 16 + lm) * 32 + quad * 8];
#pragma unroll
        for (int mt = 0; mt < 4; ++mt)
#pragma unroll
            for (int nt = 0; nt < 4; ++nt)
                acc[mt][nt] = __builtin_amdgcn_mfma_f32_16x16x32_bf16(
                    af[mt], bf[nt], acc[mt][nt], 0, 0, 0);
    }

    const bool isqk = colC < 2 * CC;   // q or k section
#pragma unroll
    for (int mt = 0; mt < 4; ++mt)
#pragma unroll
        for (int r = 0; r < 4; ++r) {
            const int row = rowC + wm * 64 + mt * 16 + quad * 4 + r;
            ushort_t* Cp = C + (size_t)row * N + colC + wn * 64 + lm;
            if (isqk) {
                const int t = row & (TT - 1);
                float ss = 0.f;
#pragma unroll
                for (int nt = 0; nt < 4; ++nt) ss += acc[mt][nt][r] * acc[mt][nt][r];
                ss += __shfl_xor(ss, 1);
                ss += __shfl_xor(ss, 2);
                ss += __shfl_xor(ss, 4);
                ss += __shfl_xor(ss, 8);
                const float rinv = rsqrtf(ss * (1.0f / 64.0f) + 1e-6f);
                const float c0 = cosb[t * 32 + lm];
                const float c1 = cosb[t * 32 + 16 + lm];
                const float s0 = sinb[t * 32 + lm];
                const float s1 = sinb[t * 32 + 16 + lm];
                const float o0 = acc[mt][0][r] * c0 + acc[mt][2][r] * s0;
                const float o1 = acc[mt][1][r] * c1 + acc[mt][3][r] * s1;
                const float o2 = acc[mt][2][r] * c0 - acc[mt][0][r] * s0;
                const float o3 = acc[mt][3][r] * c1 - acc[mt][1][r] * s1;
                Cp[0]  = f2bf(o0 * rinv);
                Cp[16] = f2bf(o1 * rinv);
                Cp[32] = f2bf(o2 * rinv);
                Cp[48] = f2bf(o3 * rinv);
            } else {
#pragma unroll
                for (int nt = 0; nt < 4; ++nt) Cp[nt * 16] = f2bf(acc[mt][nt][r]);
            }
        }
}

// ---------------------------------------------------------------------------
// bf16 MFMA flash attention, S^T formulation.
// mfma(kf, qf) -> S^T (row = key, col = q-row=lm): softmax is lane-local,
// P written as packed ushort4 row-writes into row-major P[m][key], PV via
// mfma(vf, pf) -> O^T with vectorized epilogue stores. vf shared across the
// two folded q-halves in PV; sfA/sfB never coexist (QK sequential per half).
// ---------------------------------------------------------------------------
__global__ __launch_bounds__(256, 4) void attn_mfma(const ushort_t* __restrict__ qkv,
                                                    ushort_t* __restrict__ y) {
    const int qp = blockIdx.x;   // 0..15
    const int h  = blockIdx.y;   // 0..15
    const int b  = blockIdx.z;   // 0..3
    const int tid  = threadIdx.x;
    const int w    = tid >> 6;
    const int lane = tid & 63;
    const int quad = lane >> 4;
    const int lm   = lane & 15;
    const int qtA = qp, qtB = 31 - qp;
    const int rql = w * 16 + lm;     // this lane's local q-row within q-tile

    __shared__ ushort_t Ks[64][72];     // K[key][d]
    __shared__ ushort_t Vt[64][72];     // V^T[d][key]
    __shared__ ushort_t PsA[4][16][72]; // per-wave P[m][key], half A
    __shared__ ushort_t PsB[4][16][72]; // per-wave P[m][key], half B

    short8 qfA[2], qfB[2];
    {
        const ushort_t* qa = qkv + (size_t)(b * TT + qtA * 64 + w * 16 + lm) * (3 * CC) + h * DD;
        const ushort_t* qb = qkv + (size_t)(b * TT + qtB * 64 + w * 16 + lm) * (3 * CC) + h * DD;
        qfA[0] = *(const short8*)(qa + quad * 8);
        qfA[1] = *(const short8*)(qa + 32 + quad * 8);
        qfB[0] = *(const short8*)(qb + quad * 8);
        qfB[1] = *(const short8*)(qb + 32 + quad * 8);
    }

    f32x4 OA[4], OB[4];   // O^T accumulators: row d = dt*16+quad*4+r, col m = lm
#pragma unroll
    for (int dt = 0; dt < 4; ++dt) {
        OA[dt] = (f32x4){0.f, 0.f, 0.f, 0.f};
        OB[dt] = (f32x4){0.f, 0.f, 0.f, 0.f};
    }
    float psA = 0.f, psB = 0.f;   // lane-local row sums (row lm, this quad's keys)

    // K staging: row sn, 16-col segment sd
    const int sn = tid >> 2;
    const int sd = (tid & 3) * 16;
    // V staging (micro-transpose): d-block db, token-block tb
    const int db = tid & 15;
    const int tb = tid >> 4;

    // exp2 constants: p = 2^(s*0.125*log2e - 8*log2e)
    const float K_MUL = 0.125f * 1.44269504f;
    const float K_SUB = -8.f * 1.44269504f;

    // S^T + softmax for one q-half: writes Ps[m][key], accumulates ps.
    auto qk_half = [&](short8 (&qf)[2], ushort_t (*PsW)[72], float& ps, bool diag) {
        f32x4 sf[4];
#pragma unroll
        for (int nt = 0; nt < 4; ++nt) sf[nt] = (f32x4){0.f, 0.f, 0.f, 0.f};
#pragma unroll
        for (int kk = 0; kk < 2; ++kk)
#pragma unroll
            for (int nt = 0; nt < 4; ++nt) {
                short8 kf = *(const short8*)&Ks[nt * 16 + lm][kk * 32 + quad * 8];
                sf[nt] = __builtin_amdgcn_mfma_f32_16x16x32_bf16(kf, qf[kk], sf[nt], 0, 0, 0);
            }
#pragma unroll
        for (int nt = 0; nt < 4; ++nt) {
            const int key0 = nt * 16 + quad * 4;
            ushort4 pk;
            float p0, p1, p2, p3;
            {
                float e = fmaf(sf[nt][0], K_MUL, K_SUB);
                if (diag) e = (key0 + 0 <= rql) ? e : -1e30f;
                p0 = __builtin_amdgcn_exp2f(e);
            }
            {
                float e = fmaf(sf[nt][1], K_MUL, K_SUB);
                if (diag) e = (key0 + 1 <= rql) ? e : -1e30f;
                p1 = __builtin_amdgcn_exp2f(e);
            }
            {
                float e = fmaf(sf[nt][2], K_MUL, K_SUB);
                if (diag) e = (key0 + 2 <= rql) ? e : -1e30f;
                p2 = __builtin_amdgcn_exp2f(e);
            }
            {
                float e = fmaf(sf[nt][3], K_MUL, K_SUB);
                if (diag) e = (key0 + 3 <= rql) ? e : -1e30f;
                p3 = __builtin_amdgcn_exp2f(e);
            }
            ps += (p0 + p1) + (p2 + p3);
            pk.x = f2bf(p0); pk.y = f2bf(p1); pk.z = f2bf(p2); pk.w = f2bf(p3);
            *(ushort4*)&PsW[lm][key0] = pk;
        }
    };

    for (int kt = 0; kt <= qtB; ++kt) {
        __syncthreads();
        {
            // K: 2 x b128 LDS writes
            const ushort_t* kp = qkv + (size_t)(b * TT + kt * 64 + sn) * (3 * CC) + CC + h * DD + sd;
            *(short8*)&Ks[sn][sd]     = *(const short8*)kp;
            *(short8*)&Ks[sn][sd + 8] = *(const short8*)(kp + 8);
            // V: 4 x ushort4 global loads -> 4x4 register transpose ->
            // 4 x ds_write_b64 (transient regs only)
            const ushort_t* vp = qkv + (size_t)(b * TT + kt * 64 + tb * 4) * (3 * CC) + 2 * CC + h * DD + db * 4;
            ushort4 r0 = *(const ushort4*)vp;
            ushort4 r1 = *(const ushort4*)(vp + 3 * CC);
            ushort4 r2 = *(const ushort4*)(vp + 6 * CC);
            ushort4 r3 = *(const ushort4*)(vp + 9 * CC);
            ushort4 w0 = {r0.x, r1.x, r2.x, r3.x};
            ushort4 w1 = {r0.y, r1.y, r2.y, r3.y};
            ushort4 w2 = {r0.z, r1.z, r2.z, r3.z};
            ushort4 w3 = {r0.w, r1.w, r2.w, r3.w};
            *(ushort4*)&Vt[db * 4 + 0][tb * 4] = w0;
            *(ushort4*)&Vt[db * 4 + 1][tb * 4] = w1;
            *(ushort4*)&Vt[db * 4 + 2][tb * 4] = w2;
            *(ushort4*)&Vt[db * 4 + 3][tb * 4] = w3;
        }
        __syncthreads();

        const bool doA = (kt <= qtA);

        // QK + softmax, sequential per half (sfA/sfB never coexist)
        if (doA) qk_half(qfA, PsA[w], psA, kt == qtA);
        qk_half(qfB, PsB[w], psB, kt == qtB);

        // PV: vf read once, shared by both halves
        if (doA) {
#pragma unroll
            for (int kk = 0; kk < 2; ++kk) {
                short8 pfA = *(const short8*)&PsA[w][lm][kk * 32 + quad * 8];
                short8 pfB = *(const short8*)&PsB[w][lm][kk * 32 + quad * 8];
#pragma unroll
                for (int dt = 0; dt < 4; ++dt) {
                    short8 vf = *(const short8*)&Vt[dt * 16 + lm][kk * 32 + quad * 8];
                    OA[dt] = __builtin_amdgcn_mfma_f32_16x16x32_bf16(vf, pfA, OA[dt], 0, 0, 0);
                    OB[dt] = __builtin_amdgcn_mfma_f32_16x16x32_bf16(vf, pfB, OB[dt], 0, 0, 0);
                }
            }
        } else {
#pragma unroll
            for (int kk = 0; kk < 2; ++kk) {
                short8 pfB = *(const short8*)&PsB[w][lm][kk * 32 + quad * 8];
#pragma unroll
                for (int dt = 0; dt < 4; ++dt) {
                    short8 vf = *(const short8*)&Vt[dt * 16 + lm][kk * 32 + quad * 8];
                    OB[dt] = __builtin_amdgcn_mfma_f32_16x16x32_bf16(vf, pfB, OB[dt], 0, 0, 0);
                }
            }
        }
    }

    // epilogue: O^T layout -> row q = lm, d = dt*16 + quad*4 + r.
    auto epi = [&](f32x4 (&O)[4], float ps, int qt) {
        float l = ps;
        l += __shfl_xor(l, 16);
        l += __shfl_xor(l, 32);
        const float inv_l = 1.f / l;
        ushort_t* yp = y + (size_t)(b * TT + qt * 64 + w * 16 + lm) * CC + h * DD + quad * 4;
#pragma unroll
        for (int dt = 0; dt < 4; ++dt) {
            ushort4 ov;
            ov.x = f2bf(O[dt][0] * inv_l);
            ov.y = f2bf(O[dt][1] * inv_l);
            ov.z = f2bf(O[dt][2] * inv_l);
            ov.w = f2bf(O[dt][3] * inv_l);
            *(ushort4*)(yp + dt * 16) = ov;
        }
    };
    epi(OA, psA, qtA);
    epi(OB, psB, qtB);
}

// ---------------------------------------------------------------------------
extern "C" void kernel_launch(void* const* d_in, const int* in_sizes, int n_in,
                              void* d_out, int out_size, void* d_ws, size_t ws_size,
                              hipStream_t stream) {
    const float* x      = (const float*)d_in[0];   // (4,2048,1024)
    const float* cosb   = (const float*)d_in[1];   // (1,2048,1,32)
    const float* sinb   = (const float*)d_in[2];
    const float* w_attn = (const float*)d_in[3];   // (3072,1024)
    const float* w_proj = (const float*)d_in[4];   // (1024,1024)
    float* out = (float*)d_out;                    // (4,2048,1024)

    // workspace layout (bf16 elements)
    ushort_t* qkvb = (ushort_t*)d_ws;                       // 8192*3072
    ushort_t* yb   = qkvb + (size_t)8192 * 3072;            // 8192*1024
    ushort_t* xb   = yb   + (size_t)8192 * 1024;            // 8192*1024
    ushort_t* wab  = xb   + (size_t)8192 * 1024;            // 3072*1024
    ushort_t* wpb  = wab  + (size_t)3072 * 1024;            // 1024*1024

    cast_bf16<<<(8192 * 1024 / 8 + 255) / 256, 256, 0, stream>>>(x, xb, 8192 * 1024 / 8);
    cast_bf16<<<(3072 * 1024 / 8 + 255) / 256, 256, 0, stream>>>(w_attn, wab, 3072 * 1024 / 8);
    cast_bf16<<<(1024 * 1024 / 8 + 255) / 256, 256, 0, stream>>>(w_proj, wpb, 1024 * 1024 / 8);

    // qkv = x @ w_attn^T with fused rope+rmsnorm on q,k
    gemm_qkv<<<dim3(3072 / 128, 8192 / 128), 256, 0, stream>>>(
        xb, wab, qkvb, cosb, sinb, 8192, 3072, 1024);

    // causal attention -> yb
    attn_mfma<<<dim3(16, HH, 4), 256, 0, stream>>>(qkvb, yb);

    // out = y @ w_proj^T (fp32 out)
    gemm_bt<true><<<dim3(1024 / 128, 8192 / 128), 256, 0, stream>>>(
        yb, wpb, out, 8192, 1024, 1024);
}